// Round 1
// baseline (247.100 us; speedup 1.0000x reference)
//
#include <hip/hip_runtime.h>

// Problem constants (B=32, T=1024, H=1024)
#define BB 32
#define TT 1024
#define HH 1024
#define MM (BB * TT)   // 32768 rows of the score GEMM

typedef __bf16 bf16x8 __attribute__((ext_vector_type(8)));
typedef float  f32x4  __attribute__((ext_vector_type(4)));

// ---------------- K1: h_proj[b,k] = sum_h h_t[b,h] * Wa[k,h]  (f32) -------
__global__ __launch_bounds__(256) void hproj_kernel(
    const float* __restrict__ h_t, const float* __restrict__ Wa,
    float* __restrict__ hp) {
  const int k = blockIdx.x * 256 + threadIdx.x;   // grid.x = H/256 = 4
  const int b = blockIdx.y;                       // grid.y = B  = 32
  __shared__ float hs[HH];
  for (int i = threadIdx.x; i < HH; i += 256) hs[i] = h_t[b * HH + i];
  __syncthreads();
  const float4* w  = (const float4*)(Wa + (size_t)k * HH);
  const float4* hv = (const float4*)hs;
  float acc = 0.f;
#pragma unroll 8
  for (int i = 0; i < HH / 4; ++i) {
    float4 a = w[i];
    float4 h = hv[i];
    acc += a.x * h.x + a.y * h.y + a.z * h.z + a.w * h.w;
  }
  hp[b * HH + k] = acc;
}

// ---------------- K2: fused score GEMM -----------------------------------
// e[m] += sum_{k in block cols} tanh(encproj[m,k] + hp[b,k]) * va[k]
#define BM 128
#define BN 128
#define BK 32

__device__ __forceinline__ void async_copy16(const float* g, float* l) {
  __builtin_amdgcn_global_load_lds(
      (const __attribute__((address_space(1))) void*)g,
      (__attribute__((address_space(3))) void*)l, 16, 0, 0);
}

__device__ __forceinline__ bf16x8 cvt8(const float* p) {
  f32x4 a = *(const f32x4*)p;
  f32x4 b = *(const f32x4*)(p + 4);
  bf16x8 r;
  r[0] = (__bf16)a[0]; r[1] = (__bf16)a[1]; r[2] = (__bf16)a[2]; r[3] = (__bf16)a[3];
  r[4] = (__bf16)b[0]; r[5] = (__bf16)b[1]; r[6] = (__bf16)b[2]; r[7] = (__bf16)b[3];
  return r;
}

__device__ __forceinline__ float fast_tanh(float x) {
  float e2 = __expf(2.f * x);          // v_exp_f32 path
  return 1.f - 2.f / (e2 + 1.f);       // saturates correctly at +/-1
}

__global__ __launch_bounds__(256) void score_kernel(
    const float* __restrict__ enc, const float* __restrict__ Ua,
    const float* __restrict__ hp, const float* __restrict__ va,
    float* __restrict__ e) {
  const int m0 = blockIdx.x * BM;      // grid.x = M/BM = 256
  const int n0 = blockIdx.y * BN;      // grid.y = H/BN = 8
  const int b  = m0 >> 10;             // T = 1024 => tile within one batch

  __shared__ float As[BM * BK];        // [row][k] row-major, 16 KB
  __shared__ float Bs[BN * BK];        // Ua rows (output cols), 16 KB

  const int tid  = threadIdx.x;
  const int lane = tid & 63;
  const int wid  = tid >> 6;
  const int wr   = wid >> 1;           // wave row (0..1)
  const int wc   = wid & 1;            // wave col (0..1)

  f32x4 acc[4][4] = {};

  // staging map: issue i stages rows [i*32, i*32+32); thread -> (row, 4-float col)
  const int srow = tid >> 3;           // 0..31
  const int scol = (tid & 7) * 4;      // 0,4,...,28
  const float* gA = enc + (((size_t)(m0 + srow)) << 10) + scol;
  const float* gB = Ua  + (((size_t)(n0 + srow)) << 10) + scol;
  float* lA = As + srow * BK + scol;
  float* lB = Bs + srow * BK + scol;

  for (int kt = 0; kt < HH / BK; ++kt) {
    const int h0 = kt * BK;
    __syncthreads();                   // previous compute done before overwrite
#pragma unroll
    for (int i = 0; i < 4; ++i) {
      async_copy16(gA + ((size_t)(i * 32) << 10) + h0, lA + i * 32 * BK);
      async_copy16(gB + ((size_t)(i * 32) << 10) + h0, lB + i * 32 * BK);
    }
    __syncthreads();                   // drains vmcnt: LDS tiles ready

    const int koff = (lane >> 4) * 8;  // k-slice of this lane group
    const int rl   = lane & 15;
    bf16x8 af[4], bf[4];
#pragma unroll
    for (int mi = 0; mi < 4; ++mi)
      af[mi] = cvt8(As + (wr * 64 + mi * 16 + rl) * BK + koff);
#pragma unroll
    for (int nj = 0; nj < 4; ++nj)
      bf[nj] = cvt8(Bs + (wc * 64 + nj * 16 + rl) * BK + koff);
#pragma unroll
    for (int mi = 0; mi < 4; ++mi)
#pragma unroll
      for (int nj = 0; nj < 4; ++nj)
        acc[mi][nj] = __builtin_amdgcn_mfma_f32_16x16x32_bf16(
            af[mi], bf[nj], acc[mi][nj], 0, 0, 0);
  }

  // epilogue: s = acc + hp[b, col]; partial_e[row] = sum_col tanh(s)*va[col]
  const int rl = lane & 15;
  const int rq = lane >> 4;
#pragma unroll
  for (int mi = 0; mi < 4; ++mi) {
    float rs[4] = {0.f, 0.f, 0.f, 0.f};
#pragma unroll
    for (int nj = 0; nj < 4; ++nj) {
      const int col  = n0 + wc * 64 + nj * 16 + rl;
      const float hv = hp[(b << 10) + col];
      const float vv = va[col];
#pragma unroll
      for (int j = 0; j < 4; ++j)
        rs[j] += fast_tanh(acc[mi][nj][j] + hv) * vv;
    }
#pragma unroll
    for (int j = 0; j < 4; ++j) {
      float r = rs[j];
      r += __shfl_xor(r, 1);
      r += __shfl_xor(r, 2);
      r += __shfl_xor(r, 4);
      r += __shfl_xor(r, 8);
      if (rl == 0)
        atomicAdd(&e[m0 + wr * 64 + mi * 16 + rq * 4 + j], r);
    }
  }
}

// ---------------- K3: softmax over t per b --------------------------------
__global__ __launch_bounds__(256) void softmax_kernel(
    const float* __restrict__ e, const int* __restrict__ mask,
    float* __restrict__ attn) {
  const int b   = blockIdx.x;
  const int tid = threadIdx.x;
  const float* eb = e + (b << 10);
  const int*   mb = mask + (b << 10);
  float v[4];
  float mx = -INFINITY;
#pragma unroll
  for (int j = 0; j < 4; ++j) {
    const int t = tid + j * 256;
    float x = mb[t] ? eb[t] : -INFINITY;
    v[j] = x;
    mx = fmaxf(mx, x);
  }
#pragma unroll
  for (int s = 1; s < 64; s <<= 1) mx = fmaxf(mx, __shfl_xor(mx, s));
  __shared__ float redm[4];
  if ((tid & 63) == 0) redm[tid >> 6] = mx;
  __syncthreads();
  mx = fmaxf(fmaxf(redm[0], redm[1]), fmaxf(redm[2], redm[3]));

  float s = 0.f;
#pragma unroll
  for (int j = 0; j < 4; ++j) { v[j] = __expf(v[j] - mx); s += v[j]; }
#pragma unroll
  for (int st = 1; st < 64; st <<= 1) s += __shfl_xor(s, st);
  __shared__ float reds[4];
  if ((tid & 63) == 0) reds[tid >> 6] = s;
  __syncthreads();
  s = reds[0] + reds[1] + reds[2] + reds[3];
  const float inv = 1.f / s;
#pragma unroll
  for (int j = 0; j < 4; ++j) attn[(b << 10) + tid + j * 256] = v[j] * inv;
}

// ---------------- K4: context[b,h] = sum_t attn[b,t] * enc[b,t,h] ---------
__global__ __launch_bounds__(256) void context_kernel(
    const float* __restrict__ attn, const float* __restrict__ enc,
    float* __restrict__ ctx) {
  const int h  = blockIdx.x * 256 + threadIdx.x;  // grid.x = H/256 = 4
  const int b  = blockIdx.y;                      // grid.y = B
  const int t0 = blockIdx.z * 128;                // grid.z = 8
  const float* ab = attn + (b << 10) + t0;
  const float* eb = enc + (((size_t)(b << 10) + t0) << 10) + h;
  float acc = 0.f;
#pragma unroll 4
  for (int t = 0; t < 128; ++t)
    acc = fmaf(ab[t], eb[(size_t)t << 10], acc);
  atomicAdd(&ctx[(b << 10) + h], acc);
}

// ---------------- launcher ------------------------------------------------
extern "C" void kernel_launch(void* const* d_in, const int* in_sizes, int n_in,
                              void* d_out, int out_size, void* d_ws, size_t ws_size,
                              hipStream_t stream) {
  const float* h_t  = (const float*)d_in[0];
  const float* enc  = (const float*)d_in[1];
  const int*   mask = (const int*)d_in[2];    // bool -> int32 per harness
  const float* Wa   = (const float*)d_in[3];
  const float* Ua   = (const float*)d_in[4];
  const float* va   = (const float*)d_in[5];

  float* out = (float*)d_out;      // [0,32768): context ; [32768,65536): attn
  float* e   = (float*)d_ws;       // 32768 f32 score accumulator
  float* hp  = e + MM;             // 32768 f32 h_proj

  hipMemsetAsync(e, 0, MM * sizeof(float), stream);
  hipMemsetAsync(out, 0, BB * HH * sizeof(float), stream);  // context accum

  hproj_kernel<<<dim3(HH / 256, BB), 256, 0, stream>>>(h_t, Wa, hp);
  score_kernel<<<dim3(MM / BM, HH / BN), 256, 0, stream>>>(enc, Ua, hp, va, e);
  softmax_kernel<<<BB, 256, 0, stream>>>(e, mask, out + BB * HH);
  context_kernel<<<dim3(HH / 256, BB, 8), 256, 0, stream>>>(out + BB * HH, enc, out);
}

// Round 2
// 193.089 us; speedup vs baseline: 1.2797x; 1.2797x over previous
//
#include <hip/hip_runtime.h>

// Problem constants (B=32, T=1024, H=1024)
#define BB 32
#define TT 1024
#define HH 1024
#define MM (BB * TT)   // 32768 rows of the score GEMM

typedef __bf16 bf16x8 __attribute__((ext_vector_type(8)));
typedef float  f32x4  __attribute__((ext_vector_type(4)));

__device__ __forceinline__ void async_copy16(const void* g, void* l) {
  __builtin_amdgcn_global_load_lds(
      (const __attribute__((address_space(1))) void*)g,
      (__attribute__((address_space(3))) void*)l, 16, 0, 0);
}

__device__ __forceinline__ float fast_tanh(float x) {
  float e2 = __expf(2.f * x);          // v_exp_f32 path
  return 1.f - 2.f / (e2 + 1.f);       // saturates correctly at +/-1
}

// Shared epilogue: e[row] += sum_{cols of this block} tanh(acc + hp)*va
__device__ __forceinline__ void score_epilogue(
    f32x4 acc[4][4], int m0, int n0, int b, int lane, int wr, int wc,
    const float* __restrict__ hp, const float* __restrict__ va,
    float* __restrict__ e) {
  const int rl = lane & 15;
  const int rq = lane >> 4;
#pragma unroll
  for (int mi = 0; mi < 4; ++mi) {
    float rs[4] = {0.f, 0.f, 0.f, 0.f};
#pragma unroll
    for (int nj = 0; nj < 4; ++nj) {
      const int col  = n0 + wc * 64 + nj * 16 + rl;
      const float hv = hp[(b << 10) + col];
      const float vv = va[col];
#pragma unroll
      for (int j = 0; j < 4; ++j)
        rs[j] += fast_tanh(acc[mi][nj][j] + hv) * vv;
    }
#pragma unroll
    for (int j = 0; j < 4; ++j) {
      float r = rs[j];
      r += __shfl_xor(r, 1);
      r += __shfl_xor(r, 2);
      r += __shfl_xor(r, 4);
      r += __shfl_xor(r, 8);
      if (rl == 0)
        atomicAdd(&e[m0 + wr * 64 + mi * 16 + rq * 4 + j], r);
    }
  }
}

// ---------------- K0: f32 -> bf16 pre-convert into swizzled chunk layout --
// Tile = 128 rows x 64 k (one K-step of one row-tile), 1024 chunks of 8 bf16.
// Chunk c holds (r = c>>3, g = (c&7) ^ (r&7)), i.e. LDS byte addr
// r*128 + slot*16 with slot = g ^ (r&7)  (T2 XOR swizzle, §6 G4).
// dst layout: [row_tile][16 k-steps][1024 chunks][8 bf16]
__global__ __launch_bounds__(256) void cvt_swz_kernel(
    const float* __restrict__ src, __bf16* __restrict__ dst, int nchunks) {
  const int stride = gridDim.x * 256;
  for (int F = blockIdx.x * 256 + threadIdx.x; F < nchunks; F += stride) {
    const int c  = F & 1023;
    const int t  = F >> 10;
    const int kt = t & 15;
    const int rt = t >> 4;
    const int r    = c >> 3;
    const int g    = (c & 7) ^ (r & 7);
    const size_t row = (size_t)rt * 128 + r;
    const float* s = src + (row << 10) + kt * 64 + g * 8;
    f32x4 a = *(const f32x4*)s;
    f32x4 bq = *(const f32x4*)(s + 4);
    bf16x8 o;
    o[0] = (__bf16)a[0];  o[1] = (__bf16)a[1];
    o[2] = (__bf16)a[2];  o[3] = (__bf16)a[3];
    o[4] = (__bf16)bq[0]; o[5] = (__bf16)bq[1];
    o[6] = (__bf16)bq[2]; o[7] = (__bf16)bq[3];
    *(bf16x8*)(dst + (size_t)F * 8) = o;
  }
}

// ---------------- K1: h_proj[b,k] = sum_h h_t[b,h] * Wa[k,h]  (f32) -------
__global__ __launch_bounds__(256) void hproj_kernel(
    const float* __restrict__ h_t, const float* __restrict__ Wa,
    float* __restrict__ hp) {
  const int k = blockIdx.x * 256 + threadIdx.x;
  const int b = blockIdx.y;
  __shared__ float hs[HH];
  for (int i = threadIdx.x; i < HH; i += 256) hs[i] = h_t[b * HH + i];
  __syncthreads();
  const float4* w  = (const float4*)(Wa + (size_t)k * HH);
  const float4* hv = (const float4*)hs;
  float acc = 0.f;
#pragma unroll 8
  for (int i = 0; i < HH / 4; ++i) {
    float4 a = w[i];
    float4 h = hv[i];
    acc += a.x * h.x + a.y * h.y + a.z * h.z + a.w * h.w;
  }
  hp[b * HH + k] = acc;
}

// ---------------- K2 (fast path): bf16 fused score GEMM -------------------
// BM=128, BN=128, BK=64, 4 waves (64x64 out each). LDS tiles in swizzled
// chunk layout staged linearly by global_load_lds from the pre-swizzled src.
__global__ __launch_bounds__(256) void score_bf16_kernel(
    const __bf16* __restrict__ encb, const __bf16* __restrict__ Uab,
    const float* __restrict__ hp, const float* __restrict__ va,
    float* __restrict__ e) {
  const int nt = blockIdx.x;           // 0..7   (fastest: share A tile in L2)
  const int mt = blockIdx.y;           // 0..255
  const int m0 = mt * 128;
  const int n0 = nt * 128;
  const int b  = mt >> 3;

  __shared__ __bf16 As[8192];          // 1024 chunks * 8 bf16 = 16 KB
  __shared__ __bf16 Bs[8192];

  const int tid  = threadIdx.x;
  const int lane = tid & 63;
  const int wid  = tid >> 6;
  const int wr   = wid >> 1;
  const int wc   = wid & 1;
  const int rl   = lane & 15;
  const int kq   = lane >> 4;
  const int sl0  = kq ^ (rl & 7);      // swizzled 16B-slot for kk=0

  f32x4 acc[4][4] = {};

  for (int kt = 0; kt < 16; ++kt) {
    const __bf16* ga = encb + (((size_t)(mt * 16 + kt)) << 13);  // *1024*8
    const __bf16* gb = Uab  + (((size_t)(nt * 16 + kt)) << 13);
    __syncthreads();                   // previous compute done
#pragma unroll
    for (int i = 0; i < 4; ++i) {
      const int ch = i * 256 + tid;
      async_copy16(ga + ch * 8, As + ch * 8);
      async_copy16(gb + ch * 8, Bs + ch * 8);
    }
    __syncthreads();                   // drains vmcnt: tiles ready

#pragma unroll
    for (int kk = 0; kk < 2; ++kk) {
      const int slot = sl0 ^ (kk << 2);
      bf16x8 af[4], bfr[4];
#pragma unroll
      for (int mi = 0; mi < 4; ++mi)
        af[mi] = *(const bf16x8*)(As + (wr * 64 + mi * 16 + rl) * 64 + slot * 8);
#pragma unroll
      for (int nj = 0; nj < 4; ++nj)
        bfr[nj] = *(const bf16x8*)(Bs + (wc * 64 + nj * 16 + rl) * 64 + slot * 8);
#pragma unroll
      for (int mi = 0; mi < 4; ++mi)
#pragma unroll
        for (int nj = 0; nj < 4; ++nj)
          acc[mi][nj] = __builtin_amdgcn_mfma_f32_16x16x32_bf16(
              af[mi], bfr[nj], acc[mi][nj], 0, 0, 0);
    }
  }

  score_epilogue(acc, m0, n0, b, lane, wr, wc, hp, va, e);
}

// ---------------- K2 (fallback): f32-staged score GEMM (round-1 kernel) ---
#define BM 128
#define BN 128
#define BK 32

__device__ __forceinline__ bf16x8 cvt8(const float* p) {
  f32x4 a = *(const f32x4*)p;
  f32x4 b = *(const f32x4*)(p + 4);
  bf16x8 r;
  r[0] = (__bf16)a[0]; r[1] = (__bf16)a[1]; r[2] = (__bf16)a[2]; r[3] = (__bf16)a[3];
  r[4] = (__bf16)b[0]; r[5] = (__bf16)b[1]; r[6] = (__bf16)b[2]; r[7] = (__bf16)b[3];
  return r;
}

__global__ __launch_bounds__(256) void score_f32_kernel(
    const float* __restrict__ enc, const float* __restrict__ Ua,
    const float* __restrict__ hp, const float* __restrict__ va,
    float* __restrict__ e) {
  const int m0 = blockIdx.x * BM;
  const int n0 = blockIdx.y * BN;
  const int b  = m0 >> 10;

  __shared__ float As[BM * BK];
  __shared__ float Bs[BN * BK];

  const int tid  = threadIdx.x;
  const int lane = tid & 63;
  const int wid  = tid >> 6;
  const int wr   = wid >> 1;
  const int wc   = wid & 1;

  f32x4 acc[4][4] = {};

  const int srow = tid >> 3;
  const int scol = (tid & 7) * 4;
  const float* gA = enc + (((size_t)(m0 + srow)) << 10) + scol;
  const float* gB = Ua  + (((size_t)(n0 + srow)) << 10) + scol;
  float* lA = As + srow * BK + scol;
  float* lB = Bs + srow * BK + scol;

  for (int kt = 0; kt < HH / BK; ++kt) {
    const int h0 = kt * BK;
    __syncthreads();
#pragma unroll
    for (int i = 0; i < 4; ++i) {
      async_copy16(gA + ((size_t)(i * 32) << 10) + h0, lA + i * 32 * BK);
      async_copy16(gB + ((size_t)(i * 32) << 10) + h0, lB + i * 32 * BK);
    }
    __syncthreads();

    const int koff = (lane >> 4) * 8;
    const int rl   = lane & 15;
    bf16x8 af[4], bfr[4];
#pragma unroll
    for (int mi = 0; mi < 4; ++mi)
      af[mi] = cvt8(As + (wr * 64 + mi * 16 + rl) * BK + koff);
#pragma unroll
    for (int nj = 0; nj < 4; ++nj)
      bfr[nj] = cvt8(Bs + (wc * 64 + nj * 16 + rl) * BK + koff);
#pragma unroll
    for (int mi = 0; mi < 4; ++mi)
#pragma unroll
      for (int nj = 0; nj < 4; ++nj)
        acc[mi][nj] = __builtin_amdgcn_mfma_f32_16x16x32_bf16(
            af[mi], bfr[nj], acc[mi][nj], 0, 0, 0);
  }

  score_epilogue(acc, m0, n0, b, lane, wr, wc, hp, va, e);
}

// ---------------- K3: softmax over t per b --------------------------------
__global__ __launch_bounds__(256) void softmax_kernel(
    const float* __restrict__ e, const int* __restrict__ mask,
    float* __restrict__ attn) {
  const int b   = blockIdx.x;
  const int tid = threadIdx.x;
  const float* eb = e + (b << 10);
  const int*   mb = mask + (b << 10);
  float v[4];
  float mx = -INFINITY;
#pragma unroll
  for (int j = 0; j < 4; ++j) {
    const int t = tid + j * 256;
    float x = mb[t] ? eb[t] : -INFINITY;
    v[j] = x;
    mx = fmaxf(mx, x);
  }
#pragma unroll
  for (int s = 1; s < 64; s <<= 1) mx = fmaxf(mx, __shfl_xor(mx, s));
  __shared__ float redm[4];
  if ((tid & 63) == 0) redm[tid >> 6] = mx;
  __syncthreads();
  mx = fmaxf(fmaxf(redm[0], redm[1]), fmaxf(redm[2], redm[3]));

  float s = 0.f;
#pragma unroll
  for (int j = 0; j < 4; ++j) { v[j] = __expf(v[j] - mx); s += v[j]; }
#pragma unroll
  for (int st = 1; st < 64; st <<= 1) s += __shfl_xor(s, st);
  __shared__ float reds[4];
  if ((tid & 63) == 0) reds[tid >> 6] = s;
  __syncthreads();
  s = reds[0] + reds[1] + reds[2] + reds[3];
  const float inv = 1.f / s;
#pragma unroll
  for (int j = 0; j < 4; ++j) attn[(b << 10) + tid + j * 256] = v[j] * inv;
}

// ---------------- K4: context[b,h] = sum_t attn[b,t] * enc[b,t,h] ---------
__global__ __launch_bounds__(256) void context_kernel(
    const float* __restrict__ attn, const float* __restrict__ enc,
    float* __restrict__ ctx) {
  const int h  = blockIdx.x * 256 + threadIdx.x;
  const int b  = blockIdx.y;
  const int t0 = blockIdx.z * 128;
  const float* ab = attn + (b << 10) + t0;
  const float* eb = enc + (((size_t)(b << 10) + t0) << 10) + h;
  float acc = 0.f;
#pragma unroll 4
  for (int t = 0; t < 128; ++t)
    acc = fmaf(ab[t], eb[(size_t)t << 10], acc);
  atomicAdd(&ctx[(b << 10) + h], acc);
}

// ---------------- launcher ------------------------------------------------
extern "C" void kernel_launch(void* const* d_in, const int* in_sizes, int n_in,
                              void* d_out, int out_size, void* d_ws, size_t ws_size,
                              hipStream_t stream) {
  const float* h_t  = (const float*)d_in[0];
  const float* enc  = (const float*)d_in[1];
  const int*   mask = (const int*)d_in[2];
  const float* Wa   = (const float*)d_in[3];
  const float* Ua   = (const float*)d_in[4];
  const float* va   = (const float*)d_in[5];

  float* out = (float*)d_out;      // [0,32768): context ; [32768,65536): attn
  float* e   = (float*)d_ws;       // 32768 f32 score accumulator
  float* hp  = e + MM;             // 32768 f32 h_proj

  // fast-path workspace: encb (64 MB) + Uab (2 MB) after e/hp
  const size_t base   = 2 * (size_t)MM * sizeof(float);
  const size_t encb_n = (size_t)MM * HH;           // bf16 elements
  const size_t uab_n  = (size_t)HH * HH;
  const size_t need   = base + (encb_n + uab_n) * sizeof(__bf16);

  hipMemsetAsync(e, 0, MM * sizeof(float), stream);
  hipMemsetAsync(out, 0, BB * HH * sizeof(float), stream);  // context accum

  hproj_kernel<<<dim3(HH / 256, BB), 256, 0, stream>>>(h_t, Wa, hp);

  if (ws_size >= need) {
    __bf16* encb = (__bf16*)((char*)d_ws + base);
    __bf16* uab  = encb + encb_n;
    // enc: 256 row-tiles * 16 k-steps * 1024 chunks
    cvt_swz_kernel<<<4096, 256, 0, stream>>>(enc, encb, 256 * 16 * 1024);
    // Ua: 8 row-tiles * 16 k-steps * 1024 chunks
    cvt_swz_kernel<<<512, 256, 0, stream>>>(Ua, uab, 8 * 16 * 1024);
    score_bf16_kernel<<<dim3(8, 256), 256, 0, stream>>>(encb, uab, hp, va, e);
  } else {
    score_f32_kernel<<<dim3(MM / BM, HH / BN), 256, 0, stream>>>(enc, Ua, hp, va, e);
  }

  softmax_kernel<<<BB, 256, 0, stream>>>(e, mask, out + BB * HH);
  context_kernel<<<dim3(HH / 256, BB, 8), 256, 0, stream>>>(out + BB * HH, enc, out);
}

// Round 3
// 184.919 us; speedup vs baseline: 1.3363x; 1.0442x over previous
//
#include <hip/hip_runtime.h>

// Problem constants (B=32, T=1024, H=1024)
#define BB 32
#define TT 1024
#define HH 1024
#define MM (BB * TT)   // 32768 rows of the score GEMM

typedef __bf16 bf16x8 __attribute__((ext_vector_type(8)));
typedef float  f32x4  __attribute__((ext_vector_type(4)));

__device__ __forceinline__ void async_copy16(const void* g, void* l) {
  __builtin_amdgcn_global_load_lds(
      (const __attribute__((address_space(1))) void*)g,
      (__attribute__((address_space(3))) void*)l, 16, 0, 0);
}

__device__ __forceinline__ float fast_tanh(float x) {
  float e2 = __expf(2.f * x);          // v_exp_f32 path
  return 1.f - 2.f / (e2 + 1.f);       // saturates correctly at +/-1
}

// ---------------- K0: f32 -> bf16 pre-convert into 8-phase chunk layout ---
// Per (256-row tile, K-tile kt of 64 k): 2048 chunks of 8 bf16 (32 KB).
//   chunk c = u*1024 + idx*8 + s
//   row_in_tile = (idx&63) + ((idx>>6)&1)*128 + u*64
//   logical k-slot g = s ^ (idx&7)  -> holds src[row, kt*64 + g*8 .. +8)
// Staged linearly by global_load_lds; ds_read applies the same XOR -> 0 conflicts.
__global__ __launch_bounds__(256) void cvt_swz_kernel(
    const float* __restrict__ src, __bf16* __restrict__ dst, int nchunks) {
  const int stride = gridDim.x * 256;
  for (int F = blockIdx.x * 256 + threadIdx.x; F < nchunks; F += stride) {
    const int c   = F & 2047;
    const int t   = F >> 11;          // tile*16 + kt
    const int kt  = t & 15;
    const int rt  = t >> 4;           // 256-row tile index
    const int u   = c >> 10;
    const int idx = (c >> 3) & 127;
    const int s   = c & 7;
    const int g   = s ^ (idx & 7);
    const int row = (idx & 63) + ((idx >> 6) & 1) * 128 + u * 64;
    const float* sp = src + (((size_t)rt * 256 + row) << 10) + kt * 64 + g * 8;
    f32x4 a  = *(const f32x4*)sp;
    f32x4 bq = *(const f32x4*)(sp + 4);
    bf16x8 o;
    o[0] = (__bf16)a[0];  o[1] = (__bf16)a[1];
    o[2] = (__bf16)a[2];  o[3] = (__bf16)a[3];
    o[4] = (__bf16)bq[0]; o[5] = (__bf16)bq[1];
    o[6] = (__bf16)bq[2]; o[7] = (__bf16)bq[3];
    *(bf16x8*)(dst + (size_t)F * 8) = o;
  }
}

// ---------------- K1: h_proj[b,k] = sum_h h_t[b,h] * Wa[k,h]  (f32) -------
__global__ __launch_bounds__(256) void hproj_kernel(
    const float* __restrict__ h_t, const float* __restrict__ Wa,
    float* __restrict__ hp) {
  const int k = blockIdx.x * 256 + threadIdx.x;
  const int b = blockIdx.y;
  __shared__ float hs[HH];
  for (int i = threadIdx.x; i < HH; i += 256) hs[i] = h_t[b * HH + i];
  __syncthreads();
  const float4* w  = (const float4*)(Wa + (size_t)k * HH);
  const float4* hv = (const float4*)hs;
  float acc = 0.f;
#pragma unroll 8
  for (int i = 0; i < HH / 4; ++i) {
    float4 a = w[i];
    float4 h = hv[i];
    acc += a.x * h.x + a.y * h.y + a.z * h.z + a.w * h.w;
  }
  hp[b * HH + k] = acc;
}

// ---------------- K2 (fast path): 256^2 8-phase bf16 fused score GEMM -----
// BM=BN=256, BK=64, 8 waves (2M x 4N), per-wave out 128x64. LDS 128 KiB.
// Stage units (16 KB, 2 gload_lds/thread): Ba,Bb (B u0/u1), AX (A u0), AY (A u1).
// Retirement: B fully read ph0; AX by ph1; AY by ph3. Stage plan in tile t:
//   ph0: AY(t+1) [other buf]  ph1: Ba(t+2)  ph2: Bb(t+2)  ph3: AX(t+2) [same buf,
//   regions retired >=1 phase earlier, barrier-separated]. One vmcnt(6)/K-tile.
__global__ __launch_bounds__(512, 2) void score_8ph_kernel(
    const __bf16* __restrict__ encb, const __bf16* __restrict__ uab,
    const float* __restrict__ hp, const float* __restrict__ va,
    float* __restrict__ e) {
  __shared__ __bf16 As[2][16384];   // 2 x 32 KB
  __shared__ __bf16 Bs[2][16384];   // 2 x 32 KB

  // T1 bijective chunked XCD swizzle: 512 wgs = 8 XCDs x 64
  const int wg = blockIdx.x;
  const int sw = (wg & 7) * 64 + (wg >> 3);
  const int nt = sw & 3;            // N-tile (0..3)
  const int mt = sw >> 2;           // M-tile (0..127)
  const int b  = mt >> 2;           // batch of this 256-row tile

  const int tid  = threadIdx.x;
  const int lane = tid & 63;
  const int wid  = tid >> 6;        // 0..7
  const int wr   = wid >> 2;        // 0..1
  const int wc   = wid & 3;         // 0..3
  const int rl   = lane & 15;
  const int kq   = lane >> 4;
  const int e7   = rl & 7;

  const __bf16* Ag = encb + ((size_t)(mt * 16) << 14);  // + kt<<14
  const __bf16* Bg = uab  + ((size_t)(nt * 16) << 14);

  // ds_read offset pieces (bytes)
  const int s0 = ((kq ^ e7) << 4);            // slot for kk=0
  const int s1 = (((kq + 4) ^ e7) << 4);      // slot for kk=1
  const int arow = (rl + wr * 64) * 128;      // + (mi>>2)*16384 + (mi&3)*2048
  const int brow = (rl + (wc >> 1) * 64) * 128 + (wc & 1) * 16384;  // + nj*2048

#define LDA(buf, mi, sl) (*(const bf16x8*)((const char*)(buf) + \
    (((mi) >> 2) * 16384 + ((mi) & 3) * 2048) + arow + (sl)))
#define LDB(buf, nj, sl) (*(const bf16x8*)((const char*)(buf) + \
    ((nj) * 2048) + brow + (sl)))

  // stage one 16 KB unit u of K-tile kt2 into ldsbase (2 issues/thread)
#define STAGE(gb, kt2, lp, u) do { \
    const __bf16* _g = (gb) + (((size_t)(kt2)) << 14) + (((u) << 10) + tid) * 8; \
    __bf16* _l = (lp) + (((u) << 10) + tid) * 8; \
    async_copy16(_g, _l); \
    async_copy16(_g + 4096, _l + 4096); \
  } while (0)

#define MFMA16(ml, kkb) do { \
    _Pragma("unroll") \
    for (int nj = 0; nj < 4; ++nj) { \
      acc[(ml) + 0][nj] = __builtin_amdgcn_mfma_f32_16x16x32_bf16(af0, bfr[(kkb) + nj], acc[(ml) + 0][nj], 0, 0, 0); \
      acc[(ml) + 1][nj] = __builtin_amdgcn_mfma_f32_16x16x32_bf16(af1, bfr[(kkb) + nj], acc[(ml) + 1][nj], 0, 0, 0); \
      acc[(ml) + 2][nj] = __builtin_amdgcn_mfma_f32_16x16x32_bf16(af2, bfr[(kkb) + nj], acc[(ml) + 2][nj], 0, 0, 0); \
      acc[(ml) + 3][nj] = __builtin_amdgcn_mfma_f32_16x16x32_bf16(af3, bfr[(kkb) + nj], acc[(ml) + 3][nj], 0, 0, 0); \
    } \
  } while (0)

  f32x4 acc[8][4] = {};
  bf16x8 bfr[8];

  // ---- prologue: 7 units in FIFO order, then vmcnt(6) -> tile 0 landed ----
  STAGE(Ag, 0, &As[0][0], 0);   // AX(0)
  STAGE(Bg, 0, &Bs[0][0], 0);   // Ba(0)
  STAGE(Bg, 0, &Bs[0][0], 1);   // Bb(0)
  STAGE(Ag, 0, &As[0][0], 1);   // AY(0)
  STAGE(Bg, 1, &Bs[1][0], 0);   // Ba(1)
  STAGE(Bg, 1, &Bs[1][0], 1);   // Bb(1)
  STAGE(Ag, 1, &As[1][0], 0);   // AX(1)
  asm volatile("s_waitcnt vmcnt(6)" ::: "memory");
  __builtin_amdgcn_s_barrier();

  for (int t = 0; t < 15; ++t) {
    const int p = t & 1;
    const char* Ab = (const char*)&As[p][0];
    const char* Bb = (const char*)&Bs[p][0];

    // ---- phase 0: all B frags (8) + A(kk0, m0..3); stage AY(t+1) ----
    {
#pragma unroll
      for (int nj = 0; nj < 4; ++nj) { bfr[nj] = LDB(Bb, nj, s0); bfr[4 + nj] = LDB(Bb, nj, s1); }
      bf16x8 af0 = LDA(Ab, 0, s0), af1 = LDA(Ab, 1, s0), af2 = LDA(Ab, 2, s0), af3 = LDA(Ab, 3, s0);
      STAGE(Ag, t + 1, &As[p ^ 1][0], 1);
      __builtin_amdgcn_s_barrier();
      asm volatile("s_waitcnt lgkmcnt(0)" ::: "memory");
      __builtin_amdgcn_s_setprio(1);
      MFMA16(0, 0);
      __builtin_amdgcn_s_setprio(0);
      __builtin_amdgcn_s_barrier();
    }
    // ---- phase 1: A(kk1, m0..3); stage Ba(t+2) ----
    {
      bf16x8 af0 = LDA(Ab, 0, s1), af1 = LDA(Ab, 1, s1), af2 = LDA(Ab, 2, s1), af3 = LDA(Ab, 3, s1);
      if (t < 14) STAGE(Bg, t + 2, &Bs[p][0], 0);
      __builtin_amdgcn_s_barrier();
      asm volatile("s_waitcnt lgkmcnt(0)" ::: "memory");
      __builtin_amdgcn_s_setprio(1);
      MFMA16(0, 4);
      __builtin_amdgcn_s_setprio(0);
      __builtin_amdgcn_s_barrier();
    }
    // ---- phase 2: A(kk0, m4..7); stage Bb(t+2) ----
    {
      bf16x8 af0 = LDA(Ab, 4, s0), af1 = LDA(Ab, 5, s0), af2 = LDA(Ab, 6, s0), af3 = LDA(Ab, 7, s0);
      if (t < 14) STAGE(Bg, t + 2, &Bs[p][0], 1);
      __builtin_amdgcn_s_barrier();
      asm volatile("s_waitcnt lgkmcnt(0)" ::: "memory");
      __builtin_amdgcn_s_setprio(1);
      MFMA16(4, 0);
      __builtin_amdgcn_s_setprio(0);
      __builtin_amdgcn_s_barrier();
    }
    // ---- phase 3: A(kk1, m4..7); stage AX(t+2); boundary vmcnt ----
    {
      bf16x8 af0 = LDA(Ab, 4, s1), af1 = LDA(Ab, 5, s1), af2 = LDA(Ab, 6, s1), af3 = LDA(Ab, 7, s1);
      if (t < 14) STAGE(Ag, t + 2, &As[p][0], 0);
      __builtin_amdgcn_s_barrier();
      asm volatile("s_waitcnt lgkmcnt(0)" ::: "memory");
      __builtin_amdgcn_s_setprio(1);
      MFMA16(4, 4);
      __builtin_amdgcn_s_setprio(0);
      if (t < 14) asm volatile("s_waitcnt vmcnt(6)" ::: "memory");
      else        asm volatile("s_waitcnt vmcnt(0)" ::: "memory");
      __builtin_amdgcn_s_barrier();
    }
  }

  // ---- peeled tile 15 (p=1), no staging ----
  {
    const char* Ab = (const char*)&As[1][0];
    const char* Bb = (const char*)&Bs[1][0];
    {
#pragma unroll
      for (int nj = 0; nj < 4; ++nj) { bfr[nj] = LDB(Bb, nj, s0); bfr[4 + nj] = LDB(Bb, nj, s1); }
      bf16x8 af0 = LDA(Ab, 0, s0), af1 = LDA(Ab, 1, s0), af2 = LDA(Ab, 2, s0), af3 = LDA(Ab, 3, s0);
      __builtin_amdgcn_s_barrier();
      asm volatile("s_waitcnt lgkmcnt(0)" ::: "memory");
      __builtin_amdgcn_s_setprio(1);
      MFMA16(0, 0);
      __builtin_amdgcn_s_setprio(0);
      __builtin_amdgcn_s_barrier();
    }
    {
      bf16x8 af0 = LDA(Ab, 0, s1), af1 = LDA(Ab, 1, s1), af2 = LDA(Ab, 2, s1), af3 = LDA(Ab, 3, s1);
      __builtin_amdgcn_s_barrier();
      asm volatile("s_waitcnt lgkmcnt(0)" ::: "memory");
      __builtin_amdgcn_s_setprio(1);
      MFMA16(0, 4);
      __builtin_amdgcn_s_setprio(0);
      __builtin_amdgcn_s_barrier();
    }
    {
      bf16x8 af0 = LDA(Ab, 4, s0), af1 = LDA(Ab, 5, s0), af2 = LDA(Ab, 6, s0), af3 = LDA(Ab, 7, s0);
      __builtin_amdgcn_s_barrier();
      asm volatile("s_waitcnt lgkmcnt(0)" ::: "memory");
      __builtin_amdgcn_s_setprio(1);
      MFMA16(4, 0);
      __builtin_amdgcn_s_setprio(0);
      __builtin_amdgcn_s_barrier();
    }
    {
      bf16x8 af0 = LDA(Ab, 4, s1), af1 = LDA(Ab, 5, s1), af2 = LDA(Ab, 6, s1), af3 = LDA(Ab, 7, s1);
      __builtin_amdgcn_s_barrier();
      asm volatile("s_waitcnt lgkmcnt(0)" ::: "memory");
      __builtin_amdgcn_s_setprio(1);
      MFMA16(4, 4);
      __builtin_amdgcn_s_setprio(0);
    }
  }

  // ---- epilogue: e[row] += sum_cols tanh(acc + hp)*va ----
  const float* hpb = hp + (b << 10);
#pragma unroll
  for (int mi = 0; mi < 8; ++mi) {
    float rs[4] = {0.f, 0.f, 0.f, 0.f};
#pragma unroll
    for (int nj = 0; nj < 4; ++nj) {
      const int col  = nt * 256 + wc * 64 + nj * 16 + rl;
      const float hv = hpb[col];
      const float vv = va[col];
#pragma unroll
      for (int j = 0; j < 4; ++j)
        rs[j] += fast_tanh(acc[mi][nj][j] + hv) * vv;
    }
#pragma unroll
    for (int j = 0; j < 4; ++j) {
      float r = rs[j];
      r += __shfl_xor(r, 1);
      r += __shfl_xor(r, 2);
      r += __shfl_xor(r, 4);
      r += __shfl_xor(r, 8);
      if (rl == 0)
        atomicAdd(&e[mt * 256 + wr * 128 + mi * 16 + kq * 4 + j], r);
    }
  }
#undef LDA
#undef LDB
#undef STAGE
#undef MFMA16
}

// ---------------- K2 (fallback): f32-staged score GEMM -------------------
#define BM 128
#define BN 128
#define BK 32

__device__ __forceinline__ bf16x8 cvt8(const float* p) {
  f32x4 a = *(const f32x4*)p;
  f32x4 b = *(const f32x4*)(p + 4);
  bf16x8 r;
  r[0] = (__bf16)a[0]; r[1] = (__bf16)a[1]; r[2] = (__bf16)a[2]; r[3] = (__bf16)a[3];
  r[4] = (__bf16)b[0]; r[5] = (__bf16)b[1]; r[6] = (__bf16)b[2]; r[7] = (__bf16)b[3];
  return r;
}

__device__ __forceinline__ void score_epilogue(
    f32x4 acc[4][4], int m0, int n0, int b, int lane, int wr, int wc,
    const float* __restrict__ hp, const float* __restrict__ va,
    float* __restrict__ e) {
  const int rl = lane & 15;
  const int rq = lane >> 4;
#pragma unroll
  for (int mi = 0; mi < 4; ++mi) {
    float rs[4] = {0.f, 0.f, 0.f, 0.f};
#pragma unroll
    for (int nj = 0; nj < 4; ++nj) {
      const int col  = n0 + wc * 64 + nj * 16 + rl;
      const float hv = hp[(b << 10) + col];
      const float vv = va[col];
#pragma unroll
      for (int j = 0; j < 4; ++j)
        rs[j] += fast_tanh(acc[mi][nj][j] + hv) * vv;
    }
#pragma unroll
    for (int j = 0; j < 4; ++j) {
      float r = rs[j];
      r += __shfl_xor(r, 1);
      r += __shfl_xor(r, 2);
      r += __shfl_xor(r, 4);
      r += __shfl_xor(r, 8);
      if (rl == 0)
        atomicAdd(&e[m0 + wr * 64 + mi * 16 + rq * 4 + j], r);
    }
  }
}

__global__ __launch_bounds__(256) void score_f32_kernel(
    const float* __restrict__ enc, const float* __restrict__ Ua,
    const float* __restrict__ hp, const float* __restrict__ va,
    float* __restrict__ e) {
  const int m0 = blockIdx.x * BM;
  const int n0 = blockIdx.y * BN;
  const int b  = m0 >> 10;

  __shared__ float As[BM * BK];
  __shared__ float Bs[BN * BK];

  const int tid  = threadIdx.x;
  const int lane = tid & 63;
  const int wid  = tid >> 6;
  const int wr   = wid >> 1;
  const int wc   = wid & 1;

  f32x4 acc[4][4] = {};

  const int srow = tid >> 3;
  const int scol = (tid & 7) * 4;
  const float* gA = enc + (((size_t)(m0 + srow)) << 10) + scol;
  const float* gB = Ua  + (((size_t)(n0 + srow)) << 10) + scol;
  float* lA = As + srow * BK + scol;
  float* lB = Bs + srow * BK + scol;

  for (int kt = 0; kt < HH / BK; ++kt) {
    const int h0 = kt * BK;
    __syncthreads();
#pragma unroll
    for (int i = 0; i < 4; ++i) {
      async_copy16(gA + ((size_t)(i * 32) << 10) + h0, lA + i * 32 * BK);
      async_copy16(gB + ((size_t)(i * 32) << 10) + h0, lB + i * 32 * BK);
    }
    __syncthreads();

    const int koff = (lane >> 4) * 8;
    const int rl   = lane & 15;
    bf16x8 af[4], bfr[4];
#pragma unroll
    for (int mi = 0; mi < 4; ++mi)
      af[mi] = cvt8(As + (wr * 64 + mi * 16 + rl) * BK + koff);
#pragma unroll
    for (int nj = 0; nj < 4; ++nj)
      bfr[nj] = cvt8(Bs + (wc * 64 + nj * 16 + rl) * BK + koff);
#pragma unroll
    for (int mi = 0; mi < 4; ++mi)
#pragma unroll
      for (int nj = 0; nj < 4; ++nj)
        acc[mi][nj] = __builtin_amdgcn_mfma_f32_16x16x32_bf16(
            af[mi], bfr[nj], acc[mi][nj], 0, 0, 0);
  }

  score_epilogue(acc, m0, n0, b, lane, wr, wc, hp, va, e);
}

// ---------------- K3: softmax over t per b --------------------------------
__global__ __launch_bounds__(256) void softmax_kernel(
    const float* __restrict__ e, const int* __restrict__ mask,
    float* __restrict__ attn) {
  const int b   = blockIdx.x;
  const int tid = threadIdx.x;
  const float* eb = e + (b << 10);
  const int*   mb = mask + (b << 10);
  float v[4];
  float mx = -INFINITY;
#pragma unroll
  for (int j = 0; j < 4; ++j) {
    const int t = tid + j * 256;
    float x = mb[t] ? eb[t] : -INFINITY;
    v[j] = x;
    mx = fmaxf(mx, x);
  }
#pragma unroll
  for (int s = 1; s < 64; s <<= 1) mx = fmaxf(mx, __shfl_xor(mx, s));
  __shared__ float redm[4];
  if ((tid & 63) == 0) redm[tid >> 6] = mx;
  __syncthreads();
  mx = fmaxf(fmaxf(redm[0], redm[1]), fmaxf(redm[2], redm[3]));

  float s = 0.f;
#pragma unroll
  for (int j = 0; j < 4; ++j) { v[j] = __expf(v[j] - mx); s += v[j]; }
#pragma unroll
  for (int st = 1; st < 64; st <<= 1) s += __shfl_xor(s, st);
  __shared__ float reds[4];
  if ((tid & 63) == 0) reds[tid >> 6] = s;
  __syncthreads();
  s = reds[0] + reds[1] + reds[2] + reds[3];
  const float inv = 1.f / s;
#pragma unroll
  for (int j = 0; j < 4; ++j) attn[(b << 10) + tid + j * 256] = v[j] * inv;
}

// ---------------- K4: context[b,h] = sum_t attn[b,t] * enc[b,t,h] ---------
__global__ __launch_bounds__(256) void context_kernel(
    const float* __restrict__ attn, const float* __restrict__ enc,
    float* __restrict__ ctx) {
  const int h  = blockIdx.x * 256 + threadIdx.x;
  const int b  = blockIdx.y;
  const int t0 = blockIdx.z * 128;
  const float* ab = attn + (b << 10) + t0;
  const float* eb = enc + (((size_t)(b << 10) + t0) << 10) + h;
  float acc = 0.f;
#pragma unroll 4
  for (int t = 0; t < 128; ++t)
    acc = fmaf(ab[t], eb[(size_t)t << 10], acc);
  atomicAdd(&ctx[(b << 10) + h], acc);
}

// ---------------- launcher ------------------------------------------------
extern "C" void kernel_launch(void* const* d_in, const int* in_sizes, int n_in,
                              void* d_out, int out_size, void* d_ws, size_t ws_size,
                              hipStream_t stream) {
  const float* h_t  = (const float*)d_in[0];
  const float* enc  = (const float*)d_in[1];
  const int*   mask = (const int*)d_in[2];
  const float* Wa   = (const float*)d_in[3];
  const float* Ua   = (const float*)d_in[4];
  const float* va   = (const float*)d_in[5];

  float* out = (float*)d_out;      // [0,32768): context ; [32768,65536): attn
  float* e   = (float*)d_ws;       // 32768 f32 score accumulator
  float* hp  = e + MM;             // 32768 f32 h_proj

  const size_t base   = 2 * (size_t)MM * sizeof(float);
  const size_t encb_n = (size_t)MM * HH;           // bf16 elements
  const size_t uab_n  = (size_t)HH * HH;
  const size_t need   = base + (encb_n + uab_n) * sizeof(__bf16);

  hipMemsetAsync(e, 0, MM * sizeof(float), stream);
  hipMemsetAsync(out, 0, BB * HH * sizeof(float), stream);  // context accum

  hproj_kernel<<<dim3(HH / 256, BB), 256, 0, stream>>>(h_t, Wa, hp);

  if (ws_size >= need) {
    __bf16* encb = (__bf16*)((char*)d_ws + base);
    __bf16* uab  = encb + encb_n;
    // enc: 128 row-tiles * 16 k-tiles * 2048 chunks
    cvt_swz_kernel<<<4096, 256, 0, stream>>>(enc, encb, 128 * 16 * 2048);
    // Ua: 4 row-tiles * 16 k-tiles * 2048 chunks
    cvt_swz_kernel<<<512, 256, 0, stream>>>(Ua, uab, 4 * 16 * 2048);
    score_8ph_kernel<<<512, 512, 0, stream>>>(encb, uab, hp, va, e);
  } else {
    score_f32_kernel<<<dim3(MM / BM, HH / BN), 256, 0, stream>>>(enc, Ua, hp, va, e);
  }

  softmax_kernel<<<BB, 256, 0, stream>>>(e, mask, out + BB * HH);
  context_kernel<<<dim3(HH / 256, BB, 8), 256, 0, stream>>>(out + BB * HH, enc, out);
}

// Round 4
// 176.764 us; speedup vs baseline: 1.3979x; 1.0461x over previous
//
#include <hip/hip_runtime.h>

// Problem constants (B=32, T=1024, H=1024)
#define BB 32
#define TT 1024
#define HH 1024
#define MM (BB * TT)   // 32768 rows of the score GEMM

typedef __bf16 bf16x8 __attribute__((ext_vector_type(8)));
typedef float  f32x4  __attribute__((ext_vector_type(4)));

__device__ __forceinline__ void async_copy16(const void* g, void* l) {
  __builtin_amdgcn_global_load_lds(
      (const __attribute__((address_space(1))) void*)g,
      (__attribute__((address_space(3))) void*)l, 16, 0, 0);
}

__device__ __forceinline__ float fast_tanh(float x) {
  float e2 = __expf(2.f * x);                    // v_mul + v_exp
  return 1.f - 2.f * __builtin_amdgcn_rcpf(e2 + 1.f);  // v_rcp, saturates +/-1
}

// ---------------- K0: f32 -> bf16 pre-convert into 8-phase chunk layout ---
// Per (256-row tile, K-tile kt of 64 k): 2048 chunks of 8 bf16 (32 KB).
//   chunk c = u*1024 + idx*8 + s
//   row_in_tile = (idx&63) + ((idx>>6)&1)*128 + u*64
//   logical k-slot g = s ^ (idx&7)  -> holds src[row, kt*64 + g*8 .. +8)
__global__ __launch_bounds__(256) void cvt_swz_kernel(
    const float* __restrict__ src, __bf16* __restrict__ dst, int nchunks) {
  const int stride = gridDim.x * 256;
  for (int F = blockIdx.x * 256 + threadIdx.x; F < nchunks; F += stride) {
    const int c   = F & 2047;
    const int t   = F >> 11;          // tile*16 + kt
    const int kt  = t & 15;
    const int rt  = t >> 4;           // 256-row tile index
    const int u   = c >> 10;
    const int idx = (c >> 3) & 127;
    const int s   = c & 7;
    const int g   = s ^ (idx & 7);
    const int row = (idx & 63) + ((idx >> 6) & 1) * 128 + u * 64;
    const float* sp = src + (((size_t)rt * 256 + row) << 10) + kt * 64 + g * 8;
    f32x4 a  = *(const f32x4*)sp;
    f32x4 bq = *(const f32x4*)(sp + 4);
    bf16x8 o;
    o[0] = (__bf16)a[0];  o[1] = (__bf16)a[1];
    o[2] = (__bf16)a[2];  o[3] = (__bf16)a[3];
    o[4] = (__bf16)bq[0]; o[5] = (__bf16)bq[1];
    o[6] = (__bf16)bq[2]; o[7] = (__bf16)bq[3];
    *(bf16x8*)(dst + (size_t)F * 8) = o;
  }
}

// ---------------- K1: h_proj[b,k] = sum_h h_t[b,h] * Wa[k,h]  (f32) -------
__global__ __launch_bounds__(128) void hproj_kernel(
    const float* __restrict__ h_t, const float* __restrict__ Wa,
    float* __restrict__ hp) {
  const int k = blockIdx.x * 128 + threadIdx.x;   // grid.x = 8
  const int b = blockIdx.y;                       // grid.y = 32
  __shared__ float hs[HH];
  for (int i = threadIdx.x; i < HH; i += 128) hs[i] = h_t[b * HH + i];
  __syncthreads();
  const float4* w  = (const float4*)(Wa + (size_t)k * HH);
  const float4* hv = (const float4*)hs;
  float acc = 0.f;
#pragma unroll 8
  for (int i = 0; i < HH / 4; ++i) {
    float4 a = w[i];
    float4 h = hv[i];
    acc += a.x * h.x + a.y * h.y + a.z * h.z + a.w * h.w;
  }
  hp[b * HH + k] = acc;
}

// ---------------- K2 (fast path): 256^2 8-phase bf16 fused score GEMM -----
__global__ __launch_bounds__(512, 2) void score_8ph_kernel(
    const __bf16* __restrict__ encb, const __bf16* __restrict__ uab,
    const float* __restrict__ hp, const float* __restrict__ va,
    float* __restrict__ e) {
  __shared__ __bf16 As[2][16384];   // 2 x 32 KB
  __shared__ __bf16 Bs[2][16384];   // 2 x 32 KB

  // T1 bijective chunked XCD swizzle: 512 wgs = 8 XCDs x 64
  const int wg = blockIdx.x;
  const int sw = (wg & 7) * 64 + (wg >> 3);
  const int nt = sw & 3;            // N-tile (0..3)
  const int mt = sw >> 2;           // M-tile (0..127)
  const int b  = mt >> 2;           // batch of this 256-row tile

  const int tid  = threadIdx.x;
  const int lane = tid & 63;
  const int wid  = tid >> 6;        // 0..7
  const int wr   = wid >> 2;        // 0..1
  const int wc   = wid & 3;         // 0..3
  const int rl   = lane & 15;
  const int kq   = lane >> 4;
  const int e7   = rl & 7;

  const __bf16* Ag = encb + ((size_t)(mt * 16) << 14);  // + kt<<14
  const __bf16* Bg = uab  + ((size_t)(nt * 16) << 14);

  const int s0 = ((kq ^ e7) << 4);            // slot for kk=0
  const int s1 = (((kq + 4) ^ e7) << 4);      // slot for kk=1
  const int arow = (rl + wr * 64) * 128;
  const int brow = (rl + (wc >> 1) * 64) * 128 + (wc & 1) * 16384;

#define LDA(buf, mi, sl) (*(const bf16x8*)((const char*)(buf) + \
    (((mi) >> 2) * 16384 + ((mi) & 3) * 2048) + arow + (sl)))
#define LDB(buf, nj, sl) (*(const bf16x8*)((const char*)(buf) + \
    ((nj) * 2048) + brow + (sl)))

#define STAGE(gb, kt2, lp, u) do { \
    const __bf16* _g = (gb) + (((size_t)(kt2)) << 14) + (((u) << 10) + tid) * 8; \
    __bf16* _l = (lp) + (((u) << 10) + tid) * 8; \
    async_copy16(_g, _l); \
    async_copy16(_g + 4096, _l + 4096); \
  } while (0)

#define MFMA16(ml, kkb) do { \
    _Pragma("unroll") \
    for (int nj = 0; nj < 4; ++nj) { \
      acc[(ml) + 0][nj] = __builtin_amdgcn_mfma_f32_16x16x32_bf16(af0, bfr[(kkb) + nj], acc[(ml) + 0][nj], 0, 0, 0); \
      acc[(ml) + 1][nj] = __builtin_amdgcn_mfma_f32_16x16x32_bf16(af1, bfr[(kkb) + nj], acc[(ml) + 1][nj], 0, 0, 0); \
      acc[(ml) + 2][nj] = __builtin_amdgcn_mfma_f32_16x16x32_bf16(af2, bfr[(kkb) + nj], acc[(ml) + 2][nj], 0, 0, 0); \
      acc[(ml) + 3][nj] = __builtin_amdgcn_mfma_f32_16x16x32_bf16(af3, bfr[(kkb) + nj], acc[(ml) + 3][nj], 0, 0, 0); \
    } \
  } while (0)

  f32x4 acc[8][4] = {};
  bf16x8 bfr[8];

  // ---- prologue: 7 units in FIFO order, then vmcnt(6) -> tile 0 landed ----
  STAGE(Ag, 0, &As[0][0], 0);   // AX(0)
  STAGE(Bg, 0, &Bs[0][0], 0);   // Ba(0)
  STAGE(Bg, 0, &Bs[0][0], 1);   // Bb(0)
  STAGE(Ag, 0, &As[0][0], 1);   // AY(0)
  STAGE(Bg, 1, &Bs[1][0], 0);   // Ba(1)
  STAGE(Bg, 1, &Bs[1][0], 1);   // Bb(1)
  STAGE(Ag, 1, &As[1][0], 0);   // AX(1)
  asm volatile("s_waitcnt vmcnt(6)" ::: "memory");
  __builtin_amdgcn_s_barrier();

  for (int t = 0; t < 15; ++t) {
    const int p = t & 1;
    const char* Ab = (const char*)&As[p][0];
    const char* Bb = (const char*)&Bs[p][0];

    // ---- phase 0: all B frags (8) + A(kk0, m0..3); stage AY(t+1) ----
    {
#pragma unroll
      for (int nj = 0; nj < 4; ++nj) { bfr[nj] = LDB(Bb, nj, s0); bfr[4 + nj] = LDB(Bb, nj, s1); }
      bf16x8 af0 = LDA(Ab, 0, s0), af1 = LDA(Ab, 1, s0), af2 = LDA(Ab, 2, s0), af3 = LDA(Ab, 3, s0);
      STAGE(Ag, t + 1, &As[p ^ 1][0], 1);
      __builtin_amdgcn_s_barrier();
      asm volatile("s_waitcnt lgkmcnt(0)" ::: "memory");
      __builtin_amdgcn_s_setprio(1);
      MFMA16(0, 0);
      __builtin_amdgcn_s_setprio(0);
      __builtin_amdgcn_s_barrier();
    }
    // ---- phase 1: A(kk1, m0..3); stage Ba(t+2) ----
    {
      bf16x8 af0 = LDA(Ab, 0, s1), af1 = LDA(Ab, 1, s1), af2 = LDA(Ab, 2, s1), af3 = LDA(Ab, 3, s1);
      if (t < 14) STAGE(Bg, t + 2, &Bs[p][0], 0);
      __builtin_amdgcn_s_barrier();
      asm volatile("s_waitcnt lgkmcnt(0)" ::: "memory");
      __builtin_amdgcn_s_setprio(1);
      MFMA16(0, 4);
      __builtin_amdgcn_s_setprio(0);
      __builtin_amdgcn_s_barrier();
    }
    // ---- phase 2: A(kk0, m4..7); stage Bb(t+2) ----
    {
      bf16x8 af0 = LDA(Ab, 4, s0), af1 = LDA(Ab, 5, s0), af2 = LDA(Ab, 6, s0), af3 = LDA(Ab, 7, s0);
      if (t < 14) STAGE(Bg, t + 2, &Bs[p][0], 1);
      __builtin_amdgcn_s_barrier();
      asm volatile("s_waitcnt lgkmcnt(0)" ::: "memory");
      __builtin_amdgcn_s_setprio(1);
      MFMA16(4, 0);
      __builtin_amdgcn_s_setprio(0);
      __builtin_amdgcn_s_barrier();
    }
    // ---- phase 3: A(kk1, m4..7); stage AX(t+2); boundary vmcnt ----
    {
      bf16x8 af0 = LDA(Ab, 4, s1), af1 = LDA(Ab, 5, s1), af2 = LDA(Ab, 6, s1), af3 = LDA(Ab, 7, s1);
      if (t < 14) STAGE(Ag, t + 2, &As[p][0], 0);
      __builtin_amdgcn_s_barrier();
      asm volatile("s_waitcnt lgkmcnt(0)" ::: "memory");
      __builtin_amdgcn_s_setprio(1);
      MFMA16(4, 4);
      __builtin_amdgcn_s_setprio(0);
      if (t < 14) asm volatile("s_waitcnt vmcnt(6)" ::: "memory");
      else        asm volatile("s_waitcnt vmcnt(0)" ::: "memory");
      __builtin_amdgcn_s_barrier();
    }
  }

  // ---- peeled tile 15 (p=1), no staging ----
  {
    const char* Ab = (const char*)&As[1][0];
    const char* Bb = (const char*)&Bs[1][0];
    {
#pragma unroll
      for (int nj = 0; nj < 4; ++nj) { bfr[nj] = LDB(Bb, nj, s0); bfr[4 + nj] = LDB(Bb, nj, s1); }
      bf16x8 af0 = LDA(Ab, 0, s0), af1 = LDA(Ab, 1, s0), af2 = LDA(Ab, 2, s0), af3 = LDA(Ab, 3, s0);
      __builtin_amdgcn_s_barrier();
      asm volatile("s_waitcnt lgkmcnt(0)" ::: "memory");
      __builtin_amdgcn_s_setprio(1);
      MFMA16(0, 0);
      __builtin_amdgcn_s_setprio(0);
      __builtin_amdgcn_s_barrier();
    }
    {
      bf16x8 af0 = LDA(Ab, 0, s1), af1 = LDA(Ab, 1, s1), af2 = LDA(Ab, 2, s1), af3 = LDA(Ab, 3, s1);
      __builtin_amdgcn_s_barrier();
      asm volatile("s_waitcnt lgkmcnt(0)" ::: "memory");
      __builtin_amdgcn_s_setprio(1);
      MFMA16(0, 4);
      __builtin_amdgcn_s_setprio(0);
      __builtin_amdgcn_s_barrier();
    }
    {
      bf16x8 af0 = LDA(Ab, 4, s0), af1 = LDA(Ab, 5, s0), af2 = LDA(Ab, 6, s0), af3 = LDA(Ab, 7, s0);
      __builtin_amdgcn_s_barrier();
      asm volatile("s_waitcnt lgkmcnt(0)" ::: "memory");
      __builtin_amdgcn_s_setprio(1);
      MFMA16(4, 0);
      __builtin_amdgcn_s_setprio(0);
      __builtin_amdgcn_s_barrier();
    }
    {
      bf16x8 af0 = LDA(Ab, 4, s1), af1 = LDA(Ab, 5, s1), af2 = LDA(Ab, 6, s1), af3 = LDA(Ab, 7, s1);
      __builtin_amdgcn_s_barrier();
      asm volatile("s_waitcnt lgkmcnt(0)" ::: "memory");
      __builtin_amdgcn_s_setprio(1);
      MFMA16(4, 4);
      __builtin_amdgcn_s_setprio(0);
    }
  }

  // ---- epilogue: e[row] += sum_cols tanh(acc + hp)*va ----
  const float* hpb = hp + (b << 10);
#pragma unroll
  for (int mi = 0; mi < 8; ++mi) {
    float rs[4] = {0.f, 0.f, 0.f, 0.f};
#pragma unroll
    for (int nj = 0; nj < 4; ++nj) {
      const int col  = nt * 256 + wc * 64 + nj * 16 + rl;
      const float hv = hpb[col];
      const float vv = va[col];
#pragma unroll
      for (int j = 0; j < 4; ++j)
        rs[j] += fast_tanh(acc[mi][nj][j] + hv) * vv;
    }
#pragma unroll
    for (int j = 0; j < 4; ++j) {
      float r = rs[j];
      r += __shfl_xor(r, 1);
      r += __shfl_xor(r, 2);
      r += __shfl_xor(r, 4);
      r += __shfl_xor(r, 8);
      if (rl == 0)
        atomicAdd(&e[mt * 256 + wr * 128 + mi * 16 + kq * 4 + j], r);
    }
  }
#undef LDA
#undef LDB
#undef STAGE
#undef MFMA16
}

// ---------------- K2 (fallback): f32-staged score GEMM -------------------
#define BM 128
#define BN 128
#define BK 32

__device__ __forceinline__ bf16x8 cvt8(const float* p) {
  f32x4 a = *(const f32x4*)p;
  f32x4 b = *(const f32x4*)(p + 4);
  bf16x8 r;
  r[0] = (__bf16)a[0]; r[1] = (__bf16)a[1]; r[2] = (__bf16)a[2]; r[3] = (__bf16)a[3];
  r[4] = (__bf16)b[0]; r[5] = (__bf16)b[1]; r[6] = (__bf16)b[2]; r[7] = (__bf16)b[3];
  return r;
}

__device__ __forceinline__ void score_epilogue(
    f32x4 acc[4][4], int m0, int n0, int b, int lane, int wr, int wc,
    const float* __restrict__ hp, const float* __restrict__ va,
    float* __restrict__ e) {
  const int rl = lane & 15;
  const int rq = lane >> 4;
#pragma unroll
  for (int mi = 0; mi < 4; ++mi) {
    float rs[4] = {0.f, 0.f, 0.f, 0.f};
#pragma unroll
    for (int nj = 0; nj < 4; ++nj) {
      const int col  = n0 + wc * 64 + nj * 16 + rl;
      const float hv = hp[(b << 10) + col];
      const float vv = va[col];
#pragma unroll
      for (int j = 0; j < 4; ++j)
        rs[j] += fast_tanh(acc[mi][nj][j] + hv) * vv;
    }
#pragma unroll
    for (int j = 0; j < 4; ++j) {
      float r = rs[j];
      r += __shfl_xor(r, 1);
      r += __shfl_xor(r, 2);
      r += __shfl_xor(r, 4);
      r += __shfl_xor(r, 8);
      if (rl == 0)
        atomicAdd(&e[m0 + wr * 64 + mi * 16 + rq * 4 + j], r);
    }
  }
}

__global__ __launch_bounds__(256) void score_f32_kernel(
    const float* __restrict__ enc, const float* __restrict__ Ua,
    const float* __restrict__ hp, const float* __restrict__ va,
    float* __restrict__ e) {
  const int m0 = blockIdx.x * BM;
  const int n0 = blockIdx.y * BN;
  const int b  = m0 >> 10;

  __shared__ float As[BM * BK];
  __shared__ float Bs[BN * BK];

  const int tid  = threadIdx.x;
  const int lane = tid & 63;
  const int wid  = tid >> 6;
  const int wr   = wid >> 1;
  const int wc   = wid & 1;

  f32x4 acc[4][4] = {};

  const int srow = tid >> 3;
  const int scol = (tid & 7) * 4;
  const float* gA = enc + (((size_t)(m0 + srow)) << 10) + scol;
  const float* gB = Ua  + (((size_t)(n0 + srow)) << 10) + scol;
  float* lA = As + srow * BK + scol;
  float* lB = Bs + srow * BK + scol;

  for (int kt = 0; kt < HH / BK; ++kt) {
    const int h0 = kt * BK;
    __syncthreads();
#pragma unroll
    for (int i = 0; i < 4; ++i) {
      async_copy16(gA + ((size_t)(i * 32) << 10) + h0, lA + i * 32 * BK);
      async_copy16(gB + ((size_t)(i * 32) << 10) + h0, lB + i * 32 * BK);
    }
    __syncthreads();

    const int koff = (lane >> 4) * 8;
    const int rl   = lane & 15;
    bf16x8 af[4], bfr[4];
#pragma unroll
    for (int mi = 0; mi < 4; ++mi)
      af[mi] = cvt8(As + (wr * 64 + mi * 16 + rl) * BK + koff);
#pragma unroll
    for (int nj = 0; nj < 4; ++nj)
      bfr[nj] = cvt8(Bs + (wc * 64 + nj * 16 + rl) * BK + koff);
#pragma unroll
    for (int mi = 0; mi < 4; ++mi)
#pragma unroll
      for (int nj = 0; nj < 4; ++nj)
        acc[mi][nj] = __builtin_amdgcn_mfma_f32_16x16x32_bf16(
            af[mi], bfr[nj], acc[mi][nj], 0, 0, 0);
  }

  score_epilogue(acc, m0, n0, b, lane, wr, wc, hp, va, e);
}

// ---------------- K3: softmax over t per b --------------------------------
__global__ __launch_bounds__(256) void softmax_kernel(
    const float* __restrict__ e, const int* __restrict__ mask,
    float* __restrict__ attn) {
  const int b   = blockIdx.x;
  const int tid = threadIdx.x;
  const float* eb = e + (b << 10);
  const int*   mb = mask + (b << 10);
  float v[4];
  float mx = -INFINITY;
#pragma unroll
  for (int j = 0; j < 4; ++j) {
    const int t = tid + j * 256;
    float x = mb[t] ? eb[t] : -INFINITY;
    v[j] = x;
    mx = fmaxf(mx, x);
  }
#pragma unroll
  for (int s = 1; s < 64; s <<= 1) mx = fmaxf(mx, __shfl_xor(mx, s));
  __shared__ float redm[4];
  if ((tid & 63) == 0) redm[tid >> 6] = mx;
  __syncthreads();
  mx = fmaxf(fmaxf(redm[0], redm[1]), fmaxf(redm[2], redm[3]));

  float s = 0.f;
#pragma unroll
  for (int j = 0; j < 4; ++j) { v[j] = __expf(v[j] - mx); s += v[j]; }
#pragma unroll
  for (int st = 1; st < 64; st <<= 1) s += __shfl_xor(s, st);
  __shared__ float reds[4];
  if ((tid & 63) == 0) reds[tid >> 6] = s;
  __syncthreads();
  s = reds[0] + reds[1] + reds[2] + reds[3];
  const float inv = 1.f / s;
#pragma unroll
  for (int j = 0; j < 4; ++j) attn[(b << 10) + tid + j * 256] = v[j] * inv;
}

// ---------------- K4 (fast): context from swizzled bf16 encb --------------
// ctx[b,h] = sum_t attn[b,t] * enc[b,t,h].  Thread owns 8 consecutive h
// (one chunk-elem group) and 64 t; element address in encb:
//   elem = ((rt*16+kt)<<14) + u*8192 + idx*64 + s*8 + e
//   u=(r>>6)&1, b7=(r>>7)&1, idx=(r&63)+64*b7, s=(h8&7)^(r&7), r=t&255
__global__ __launch_bounds__(256) void context_bf16_kernel(
    const __bf16* __restrict__ encb, const float* __restrict__ attn,
    float* __restrict__ ctx) {
  const int b   = blockIdx.y;
  const int bz  = blockIdx.z;         // t-block of 128 (0..7)
  const int tid = threadIdx.x;
  const int h8  = tid & 127;          // chunk-of-8 h index (0..127)
  const int th  = tid >> 7;           // t-half (0..1) == u
  const int kt  = h8 >> 3;
  const int g   = h8 & 7;

  __shared__ float at[128];
  if (tid < 128) at[tid] = attn[(b << 10) + bz * 128 + tid];
  __syncthreads();

  const int rt = b * 4 + (bz >> 1);
  const int b7 = bz & 1;
  const __bf16* base = encb + (((size_t)(rt * 16 + kt)) << 14)
                       + (th << 13) + (b7 << 12);
  const float* atp = at + th * 64;

  float acc[8] = {};
#pragma unroll 8
  for (int j = 0; j < 64; ++j) {
    const int s = g ^ (j & 7);
    bf16x8 v = *(const bf16x8*)(base + j * 64 + s * 8);
    const float w = atp[j];
#pragma unroll
    for (int ee = 0; ee < 8; ++ee) acc[ee] += w * (float)v[ee];
  }
  float* cp = ctx + (b << 10) + h8 * 8;
#pragma unroll
  for (int ee = 0; ee < 8; ++ee) atomicAdd(cp + ee, acc[ee]);
}

// ---------------- K4 (fallback): f32 context ------------------------------
__global__ __launch_bounds__(256) void context_kernel(
    const float* __restrict__ attn, const float* __restrict__ enc,
    float* __restrict__ ctx) {
  const int h  = blockIdx.x * 256 + threadIdx.x;
  const int b  = blockIdx.y;
  const int t0 = blockIdx.z * 128;
  const float* ab = attn + (b << 10) + t0;
  const float* eb = enc + (((size_t)(b << 10) + t0) << 10) + h;
  float acc = 0.f;
#pragma unroll 4
  for (int t = 0; t < 128; ++t)
    acc = fmaf(ab[t], eb[(size_t)t << 10], acc);
  atomicAdd(&ctx[(b << 10) + h], acc);
}

// ---------------- launcher ------------------------------------------------
extern "C" void kernel_launch(void* const* d_in, const int* in_sizes, int n_in,
                              void* d_out, int out_size, void* d_ws, size_t ws_size,
                              hipStream_t stream) {
  const float* h_t  = (const float*)d_in[0];
  const float* enc  = (const float*)d_in[1];
  const int*   mask = (const int*)d_in[2];
  const float* Wa   = (const float*)d_in[3];
  const float* Ua   = (const float*)d_in[4];
  const float* va   = (const float*)d_in[5];

  float* out = (float*)d_out;      // [0,32768): context ; [32768,65536): attn
  float* e   = (float*)d_ws;       // 32768 f32 score accumulator
  float* hp  = e + MM;             // 32768 f32 h_proj

  const size_t base   = 2 * (size_t)MM * sizeof(float);
  const size_t encb_n = (size_t)MM * HH;           // bf16 elements
  const size_t uab_n  = (size_t)HH * HH;
  const size_t need   = base + (encb_n + uab_n) * sizeof(__bf16);

  hipMemsetAsync(e, 0, MM * sizeof(float), stream);
  hipMemsetAsync(out, 0, BB * HH * sizeof(float), stream);  // context accum

  hproj_kernel<<<dim3(HH / 128, BB), 128, 0, stream>>>(h_t, Wa, hp);

  if (ws_size >= need) {
    __bf16* encb = (__bf16*)((char*)d_ws + base);
    __bf16* uab  = encb + encb_n;
    cvt_swz_kernel<<<4096, 256, 0, stream>>>(enc, encb, 128 * 16 * 2048);
    cvt_swz_kernel<<<512, 256, 0, stream>>>(Ua, uab, 4 * 16 * 2048);
    score_8ph_kernel<<<512, 512, 0, stream>>>(encb, uab, hp, va, e);
    softmax_kernel<<<BB, 256, 0, stream>>>(e, mask, out + BB * HH);
    context_bf16_kernel<<<dim3(1, BB, 8), 256, 0, stream>>>(
        encb, out + BB * HH, out);
  } else {
    score_f32_kernel<<<dim3(MM / BM, HH / BN), 256, 0, stream>>>(enc, Ua, hp, va, e);
    softmax_kernel<<<BB, 256, 0, stream>>>(e, mask, out + BB * HH);
    context_kernel<<<dim3(HH / 256, BB, 8), 256, 0, stream>>>(out + BB * HH, enc, out);
  }
}